// Round 9
// baseline (587.633 us; speedup 1.0000x reference)
//
#include <hip/hip_runtime.h>

// Problem constants (reference: Q=2048, N=100000, D=512, K=32)
#define QN    2048
#define NN    100000
#define DD    512
#define NPAD  100352        // 784 col-tiles of 128
#define NCT   784
#define CAP   1024          // per-query candidate capacity

typedef unsigned short u16;
typedef unsigned int   u32;
typedef unsigned long long u64;
typedef __attribute__((__ext_vector_type__(8))) short  bf16x8_t;  // 8 bf16 in 4 VGPRs
typedef __attribute__((__ext_vector_type__(4))) float  f32x4_t;

// ---- helpers -------------------------------------------------------------

// fp32 -> bf16 bits, round-to-nearest-even (inputs are finite)
__device__ __forceinline__ u16 f2bf(float f) {
  u32 u = __float_as_uint(f);
  u32 r = (u + 0x7FFFu + ((u >> 16) & 1u)) >> 16;
  return (u16)r;
}

// linear monotone u16 quantization of score s = 0.5*||m||^2 - q.m
__device__ __forceinline__ u16 qkey_of(float s) {
  float t = (s + 32.0f) * (65536.0f / 576.0f);
  t = fminf(fmaxf(t, 0.0f), 65535.0f);
  return (u16)(u32)t;
}

// async global->LDS, 16B per lane; LDS dest = wave-uniform base + lane*16
__device__ __forceinline__ void gload_lds16(const u16* g, u16* l) {
  __builtin_amdgcn_global_load_lds((const __attribute__((address_space(1))) void*)g,
                                   (__attribute__((address_space(3))) void*)l,
                                   16, 0, 0);
}

// Two-level byte histogram rank-select over `cnt` keys (15-bit values in u16)
// in LDS. First level buckets keys>>8 (0..127), second level keys&255.
__device__ void rank_cutoff(const u16* keys, int cnt, u32 kwant,
                            u32* hist, u32* cum, u32* scal, int tid,
                            u32& kstar, u32& need) {
  hist[tid] = 0;
  __syncthreads();
  for (int i = tid; i < cnt; i += 256) atomicAdd(&hist[keys[i] >> 8], 1u);
  __syncthreads();
  if (tid < 64) {
    u32 h0 = hist[4*tid], h1 = hist[4*tid+1], h2 = hist[4*tid+2], h3 = hist[4*tid+3];
    u32 s = h0 + h1 + h2 + h3, incl = s;
    #pragma unroll
    for (int off = 1; off < 64; off <<= 1) { u32 t = __shfl_up(incl, off); if (tid >= off) incl += t; }
    u32 base = incl - s;
    cum[4*tid] = base + h0; cum[4*tid+1] = base + h0 + h1;
    cum[4*tid+2] = base + h0 + h1 + h2; cum[4*tid+3] = incl;
  }
  __syncthreads();
  { u32 c = cum[tid], p = tid ? cum[tid-1] : 0u;
    if (c >= kwant && p < kwant) { scal[0] = (u32)tid; scal[1] = p; } }
  __syncthreads();
  u32 b = scal[0], before = scal[1];
  __syncthreads();
  hist[tid] = 0;
  __syncthreads();
  for (int i = tid; i < cnt; i += 256) {
    u16 kk = keys[i];
    if ((u32)(kk >> 8) == b) atomicAdd(&hist[kk & 255u], 1u);
  }
  __syncthreads();
  if (tid < 64) {
    u32 h0 = hist[4*tid], h1 = hist[4*tid+1], h2 = hist[4*tid+2], h3 = hist[4*tid+3];
    u32 s = h0 + h1 + h2 + h3, incl = s;
    #pragma unroll
    for (int off = 1; off < 64; off <<= 1) { u32 t = __shfl_up(incl, off); if (tid >= off) incl += t; }
    u32 base = incl - s;
    cum[4*tid] = base + h0; cum[4*tid+1] = base + h0 + h1;
    cum[4*tid+2] = base + h0 + h1 + h2; cum[4*tid+3] = incl;
  }
  __syncthreads();
  { u32 c = before + cum[tid], p = before + (tid ? cum[tid-1] : 0u);
    if (c >= kwant && p < kwant) { scal[0] = (b << 8) | (u32)tid; scal[1] = kwant - p; } }
  __syncthreads();
  kstar = scal[0]; need = scal[1];
  __syncthreads();
}

// ---- packing -------------------------------------------------------------
// Round-1 verified tile-contiguous, XOR8-swizzled layout (measured 0 LDS
// bank conflicts):
//   tile t = (rt, kstep): rows rt*128..+128, k kstep*64..+64, 16KB contiguous
//   at u16 offset (rt*8 + kstep)*8192.
//   within tile: element (rl, kl) at  rl*64 + (((kl>>3) ^ (rl&7))<<3) + (kl&7)
// Staging is a LINEAR lane*16B gload_lds copy (linear LDS dest + pre-swizzled
// global source), so LDS gets the same XOR layout; fragment ds_read_b128 at
//   rl*128B + (((ks*4+quad) ^ (m16&7))*16B)
// spreads 64 lanes uniformly over all 32 banks.

// FUSED prep: blocks [0, NPAD/4) pack B (pad rows zero) + mm[j]=||m_j||^2;
// blocks [NPAD/4, NPAD/4+QN/4) pack A as bf16(-q) + theta + cnt=0.
__global__ __launch_bounds__(256) void k_prep(const float* __restrict__ B,
                                              u16* __restrict__ Bpack,
                                              float* __restrict__ mm,
                                              const float* __restrict__ A,
                                              u16* __restrict__ Apack,
                                              float* __restrict__ theta,
                                              u32* __restrict__ cnt) {
  const int blk = blockIdx.x;
  if (blk < NPAD / 4) {
    int g = blk * 256 + threadIdx.x;
    int row = g >> 6, lane = g & 63;
    const int rt = row >> 7, rl = row & 127;
    const int kstep = lane >> 3, chunk = lane & 7;
    u16* dst = Bpack + (size_t)(rt * 8 + kstep) * 8192
             + rl * 64 + ((chunk ^ (rl & 7)) << 3);
    if (row < NN) {
      const float* r = B + (size_t)row * DD + lane * 8;
      float4 a = *(const float4*)&r[0];
      float4 b = *(const float4*)&r[4];
      ushort4 h0, h1;
      h0.x = f2bf(a.x); h0.y = f2bf(a.y); h0.z = f2bf(a.z); h0.w = f2bf(a.w);
      h1.x = f2bf(b.x); h1.y = f2bf(b.y); h1.z = f2bf(b.z); h1.w = f2bf(b.w);
      *(ushort4*)&dst[0] = h0; *(ushort4*)&dst[4] = h1;
      float s = a.x*a.x + a.y*a.y + a.z*a.z + a.w*a.w
              + b.x*b.x + b.y*b.y + b.z*b.z + b.w*b.w;
      #pragma unroll
      for (int off = 32; off; off >>= 1) s += __shfl_xor(s, off);
      if (lane == 0) mm[row] = s;
    } else {
      ushort4 z; z.x = 0; z.y = 0; z.z = 0; z.w = 0;
      *(ushort4*)&dst[0] = z; *(ushort4*)&dst[4] = z;
      if (lane == 0) mm[row] = 1e30f;
    }
  } else {
    int g = (blk - NPAD / 4) * 256 + threadIdx.x;
    int row = g >> 6, lane = g & 63;
    const int qt = row >> 7, rl = row & 127;
    const int kstep = lane >> 3, chunk = lane & 7;
    u16* dst = Apack + (size_t)(qt * 8 + kstep) * 8192
             + rl * 64 + ((chunk ^ (rl & 7)) << 3);
    const float* r = A + (size_t)row * DD + lane * 8;
    float4 a = *(const float4*)&r[0];
    float4 b = *(const float4*)&r[4];
    ushort4 h0, h1;
    h0.x = f2bf(-a.x); h0.y = f2bf(-a.y); h0.z = f2bf(-a.z); h0.w = f2bf(-a.w);
    h1.x = f2bf(-b.x); h1.y = f2bf(-b.y); h1.z = f2bf(-b.z); h1.w = f2bf(-b.w);
    *(ushort4*)&dst[0] = h0; *(ushort4*)&dst[4] = h1;
    float s = a.x*a.x + a.y*a.y + a.z*a.z + a.w*a.w
            + b.x*b.x + b.y*b.y + b.z*b.z + b.w*b.w;
    #pragma unroll
    for (int off = 32; off; off >>= 1) s += __shfl_xor(s, off);
    if (lane == 0) {
      theta[row] = 256.0f - 2.9f * sqrtf(256.0f + s);
      cnt[row] = 0u;
    }
  }
}

// Screening GEMM — ROUND-1 CHAMPION structure (280 us, 752 TF, 0 conflicts):
// 128x128 tile, BK=64, 4 waves (2x2), single-buffer LDS staged via
// global_load_lds width-16, 2-barrier K-loop, ~3 blocks/CU mutual overlap.
// Only change vs R8: candidate entries packed to u32 (15-bit key + 17-bit
// col) — halves cands write traffic; exact fp64 rescore in k_merge makes
// the coarser key harmless (top-32 vs rank-64 margin >> 0.018 score units).
__global__ __launch_bounds__(256, 2) void k_gemm(const u16* __restrict__ Apack,
                                                 const u16* __restrict__ Bpack,
                                                 const float* __restrict__ mm,
                                                 const float* __restrict__ theta,
                                                 u32* __restrict__ cnt,
                                                 u32* __restrict__ cands) {
  __shared__ __align__(16) u16 Alds[8192];   // 128 rows x 64 k, XOR8-swizzled
  __shared__ __align__(16) u16 Blds[8192];
  const int tid  = threadIdx.x;
  const int lane = tid & 63;
  const int w    = tid >> 6;
  const int wq   = w >> 1, wn = w & 1;
  const int quad = lane >> 4, m16 = lane & 15;

  // XCD-band mapping: b%8 = XCD x, each XCD owns col-tiles [x*98, x*98+98);
  // 16 consecutive same-XCD blocks share one B-tile (L2-resident).
  const int b  = blockIdx.x;
  const int x  = b & 7, kk_ = b >> 3;
  const int ct = x * 98 + (kk_ >> 4);
  const int qt = kk_ & 15;
  const int q0   = qt * 128;
  const int col0 = ct * 128;

  f32x4_t acc[4][4];
  #pragma unroll
  for (int j = 0; j < 4; j++) {
    float mv = 0.5f * mm[col0 + wn * 64 + j * 16 + m16];
    #pragma unroll
    for (int i = 0; i < 4; i++) { acc[i][j][0] = mv; acc[i][j][1] = mv; acc[i][j][2] = mv; acc[i][j][3] = mv; }
  }

  const u16* gA = Apack + (size_t)qt * 65536;   // 8 ksteps x 8192 u16
  const u16* gB = Bpack + (size_t)ct * 65536;

  const int sa  = m16 & 7;
  const int ch0 = ((0 * 4 + quad) ^ sa) << 3;   // u16 offset of 16B chunk, ks=0
  const int ch1 = ((1 * 4 + quad) ^ sa) << 3;   // ks=1
  const int aBase = (wq * 64 + m16) * 64;
  const int bBase = (wn * 64 + m16) * 64;
  const int c0 = w * 4;                          // this wave's four 1KB chunks

  #pragma unroll 1
  for (int kstep = 0; kstep < 8; ++kstep) {
    if (kstep) __syncthreads();                  // LDS reuse guard
    const u16* sA = gA + kstep * 8192;
    const u16* sB = gB + kstep * 8192;
    #pragma unroll
    for (int l = 0; l < 4; ++l) {
      const int c = c0 + l;
      gload_lds16(sA + c * 512 + lane * 8, &Alds[c * 512]);
      gload_lds16(sB + c * 512 + lane * 8, &Blds[c * 512]);
    }
    __syncthreads();                             // vmcnt(0) drain + barrier

    bf16x8_t af[2][4], bff[2][4];
    #pragma unroll
    for (int i = 0; i < 4; ++i) {
      af[0][i] = *(const bf16x8_t*)&Alds[aBase + i * 1024 + ch0];
      af[1][i] = *(const bf16x8_t*)&Alds[aBase + i * 1024 + ch1];
    }
    #pragma unroll
    for (int j = 0; j < 4; ++j) {
      bff[0][j] = *(const bf16x8_t*)&Blds[bBase + j * 1024 + ch0];
      bff[1][j] = *(const bf16x8_t*)&Blds[bBase + j * 1024 + ch1];
    }
    #pragma unroll
    for (int ks = 0; ks < 2; ++ks)
      #pragma unroll
      for (int i = 0; i < 4; ++i)
        #pragma unroll
        for (int j = 0; j < 4; ++j)
          acc[i][j] = __builtin_amdgcn_mfma_f32_16x16x32_bf16(af[ks][i], bff[ks][j], acc[i][j], 0, 0, 0);
  }

  // epilogue: C/D layout col=lane&15, row=(lane>>4)*4+reg; rare-hit append.
  #pragma unroll
  for (int i = 0; i < 4; i++) {
    #pragma unroll
    for (int r = 0; r < 4; r++) {
      int qrow = q0 + wq * 64 + i * 16 + quad * 4 + r;
      float th = theta[qrow];
      #pragma unroll
      for (int j = 0; j < 4; j++) {
        float s = acc[i][j][r];
        if (s < th) {
          int col = col0 + wn * 64 + j * 16 + m16;
          u32 slot = atomicAdd(&cnt[qrow], 1u);
          if (slot < CAP) {
            u32 key15 = (u32)qkey_of(s) >> 1;
            cands[(size_t)qrow * CAP + slot] = (key15 << 17) | (u32)col;
          }
        }
      }
    }
  }
}

// Per query: rank-select candidates -> top-64 by 15-bit key, rescore exactly
// in fp64, bitonic-sort 64, mean of top-32 true_values.
__global__ __launch_bounds__(256) void k_merge(const u32* __restrict__ cnt,
                                               const u32* __restrict__ cands,
                                               const float* __restrict__ A,
                                               const float* __restrict__ B,
                                               const float* __restrict__ tv,
                                               float* __restrict__ out) {
  int tid = threadIdx.x, q = blockIdx.x;
  __shared__ u16 keys[CAP];
  __shared__ int idxs[CAP];
  __shared__ u32 hist[256], cum[256], scal[2];
  __shared__ int cand[64];
  __shared__ float qrow[512];
  __shared__ double dd[64];

  int c = (int)min(cnt[q], (u32)CAP);
  for (int i = tid; i < c; i += 256) {
    u32 e = cands[(size_t)q * CAP + i];
    keys[i] = (u16)(e >> 17);
    idxs[i] = (int)(e & 0x1FFFFu);
  }
  __syncthreads();
  u32 kwant = (c < 64) ? (u32)c : 64u;
  if (c <= 64) {
    // fast path (block-uniform): all candidates survive; skip rank-select
    for (int i = tid; i < c; i += 256) cand[i] = idxs[i];
  } else {
    u32 kstar, need;
    rank_cutoff(keys, c, kwant, hist, cum, scal, tid, kstar, need);
    if (tid == 0) { scal[0] = 0; scal[1] = 0; }
    __syncthreads();
    for (int i = tid; i < c; i += 256) {
      u16 kk = keys[i];
      if (kk < (u16)kstar) { u32 p = atomicAdd(&scal[0], 1u); cand[p] = idxs[i]; }
      else if (kk == (u16)kstar) {
        u32 t = atomicAdd(&scal[1], 1u);
        if (t < need) { u32 p = atomicAdd(&scal[0], 1u); cand[p] = idxs[i]; }
      }
    }
  }
  for (int i = tid; i < 512; i += 256) qrow[i] = A[(size_t)q * DD + i];
  __syncthreads();
  const int NC = (int)kwant;

  int w = tid >> 6, lane = tid & 63;
  double qd[8];
  #pragma unroll
  for (int e = 0; e < 8; e++) qd[e] = (double)qrow[lane * 8 + e];
  #pragma unroll 2
  for (int cc = w; cc < 64; cc += 4) {
    if (cc < NC) {
      const float* mrow = B + (size_t)cand[cc] * DD;
      float4 m0 = *(const float4*)&mrow[lane * 8];
      float4 m1 = *(const float4*)&mrow[lane * 8 + 4];
      double a = 0.0, t;
      t = qd[0] - (double)m0.x; a = fma(t, t, a);
      t = qd[1] - (double)m0.y; a = fma(t, t, a);
      t = qd[2] - (double)m0.z; a = fma(t, t, a);
      t = qd[3] - (double)m0.w; a = fma(t, t, a);
      t = qd[4] - (double)m1.x; a = fma(t, t, a);
      t = qd[5] - (double)m1.y; a = fma(t, t, a);
      t = qd[6] - (double)m1.z; a = fma(t, t, a);
      t = qd[7] - (double)m1.w; a = fma(t, t, a);
      #pragma unroll
      for (int off = 32; off; off >>= 1) a += __shfl_xor(a, off);
      if (lane == 0) dd[cc] = a;
    } else {
      if (lane == 0) dd[cc] = 1e300;
    }
  }
  __syncthreads();
  if (w == 0) {
    double d = dd[lane];
    float v = (lane < NC) ? tv[cand[lane]] : 0.0f;
    #pragma unroll
    for (int k = 2; k <= 64; k <<= 1) {
      #pragma unroll
      for (int j = k >> 1; j > 0; j >>= 1) {
        int partner = lane ^ j;
        double od = __shfl_xor(d, j);
        float  ovv = __shfl_xor(v, j);
        bool up = ((lane & k) == 0);
        bool takeMin = (lane < partner) == up;
        bool sw = takeMin ? (od < d) : (od > d);
        if (sw) { d = od; v = ovv; }
      }
    }
    double s = (lane < 32) ? (double)v : 0.0;
    #pragma unroll
    for (int off = 32; off; off >>= 1) s += __shfl_xor(s, off);
    if (lane == 0) out[q] = (float)(s * (1.0 / 32.0));
  }
}

// ---- launcher ------------------------------------------------------------

extern "C" void kernel_launch(void* const* d_in, const int* in_sizes, int n_in,
                              void* d_out, int out_size, void* d_ws, size_t ws_size,
                              hipStream_t stream) {
  const float* A  = (const float*)d_in[0];   // h_query      [2048,512]
  const float* B  = (const float*)d_in[1];   // memory_embeds[100000,512]
  const float* tv = (const float*)d_in[2];   // true_values  [100000]
  float* out = (float*)d_out;                // [2048]
  char* ws = (char*)d_ws;
  // ws layout (~114 MB of ~800 MB)
  float* mm    = (float*)(ws);                  // 100352 f32
  u16*   Apack = (u16*)  (ws + 401408);         // 2048*512 bf16, tile-swizzled
  float* theta = (float*)(ws + 2498560);        // 2048 f32
  u32*   cnt   = (u32*)  (ws + 2506752);        // 2048 u32
  u16*   Bpack = (u16*)  (ws + 2514944);        // 100352*512 bf16, tile-swizzled
  u32*   cands = (u32*)  (ws + 105275392);      // 2048*1024 u32 (8.4 MB)

  k_prep <<<NPAD / 4 + QN / 4, 256, 0, stream>>>(B, Bpack, mm, A, Apack, theta, cnt);
  k_gemm <<<NCT * 16, 256, 0, stream>>>(Apack, Bpack, mm, theta, cnt, cands);
  k_merge<<<QN, 256, 0, stream>>>(cnt, cands, A, B, tv, out);
}

// Round 10
// 562.324 us; speedup vs baseline: 1.0450x; 1.0450x over previous
//
#include <hip/hip_runtime.h>

// Problem constants (reference: Q=2048, N=100000, D=512, K=32)
#define QN    2048
#define NN    100000
#define DD    512
#define NPAD  100352        // 784 col-tiles of 128
#define NCT   784
#define CAP   1024          // per-query candidate capacity

typedef unsigned short u16;
typedef unsigned int   u32;
typedef unsigned long long u64;
typedef __attribute__((__ext_vector_type__(8))) short  bf16x8_t;  // 8 bf16 in 4 VGPRs
typedef __attribute__((__ext_vector_type__(4))) float  f32x4_t;

// ---- helpers -------------------------------------------------------------

// fp32 -> bf16 bits, round-to-nearest-even (inputs are finite)
__device__ __forceinline__ u16 f2bf(float f) {
  u32 u = __float_as_uint(f);
  u32 r = (u + 0x7FFFu + ((u >> 16) & 1u)) >> 16;
  return (u16)r;
}

// linear monotone u16 quantization of score s = 0.5*||m||^2 - q.m
__device__ __forceinline__ u16 qkey_of(float s) {
  float t = (s + 32.0f) * (65536.0f / 576.0f);
  t = fminf(fmaxf(t, 0.0f), 65535.0f);
  return (u16)(u32)t;
}

// async global->LDS, 16B per lane; LDS dest = wave-uniform base + lane*16
__device__ __forceinline__ void gload_lds16(const u16* g, u16* l) {
  __builtin_amdgcn_global_load_lds((const __attribute__((address_space(1))) void*)g,
                                   (__attribute__((address_space(3))) void*)l,
                                   16, 0, 0);
}

// Two-level byte histogram rank-select over `cnt` u16 keys in LDS.
__device__ void rank_cutoff(const u16* keys, int cnt, u32 kwant,
                            u32* hist, u32* cum, u32* scal, int tid,
                            u32& kstar, u32& need) {
  hist[tid] = 0;
  __syncthreads();
  for (int i = tid; i < cnt; i += 256) atomicAdd(&hist[keys[i] >> 8], 1u);
  __syncthreads();
  if (tid < 64) {
    u32 h0 = hist[4*tid], h1 = hist[4*tid+1], h2 = hist[4*tid+2], h3 = hist[4*tid+3];
    u32 s = h0 + h1 + h2 + h3, incl = s;
    #pragma unroll
    for (int off = 1; off < 64; off <<= 1) { u32 t = __shfl_up(incl, off); if (tid >= off) incl += t; }
    u32 base = incl - s;
    cum[4*tid] = base + h0; cum[4*tid+1] = base + h0 + h1;
    cum[4*tid+2] = base + h0 + h1 + h2; cum[4*tid+3] = incl;
  }
  __syncthreads();
  { u32 c = cum[tid], p = tid ? cum[tid-1] : 0u;
    if (c >= kwant && p < kwant) { scal[0] = (u32)tid; scal[1] = p; } }
  __syncthreads();
  u32 b = scal[0], before = scal[1];
  __syncthreads();
  hist[tid] = 0;
  __syncthreads();
  for (int i = tid; i < cnt; i += 256) {
    u16 kk = keys[i];
    if ((u32)(kk >> 8) == b) atomicAdd(&hist[kk & 255u], 1u);
  }
  __syncthreads();
  if (tid < 64) {
    u32 h0 = hist[4*tid], h1 = hist[4*tid+1], h2 = hist[4*tid+2], h3 = hist[4*tid+3];
    u32 s = h0 + h1 + h2 + h3, incl = s;
    #pragma unroll
    for (int off = 1; off < 64; off <<= 1) { u32 t = __shfl_up(incl, off); if (tid >= off) incl += t; }
    u32 base = incl - s;
    cum[4*tid] = base + h0; cum[4*tid+1] = base + h0 + h1;
    cum[4*tid+2] = base + h0 + h1 + h2; cum[4*tid+3] = incl;
  }
  __syncthreads();
  { u32 c = before + cum[tid], p = before + (tid ? cum[tid-1] : 0u);
    if (c >= kwant && p < kwant) { scal[0] = (b << 8) | (u32)tid; scal[1] = kwant - p; } }
  __syncthreads();
  kstar = scal[0]; need = scal[1];
  __syncthreads();
}

// ---- packing -------------------------------------------------------------
// Round-1 verified tile-contiguous, XOR8-swizzled layout (measured 0 LDS
// bank conflicts):
//   tile t = (rt, kstep): rows rt*128..+128, k kstep*64..+64, 16KB contiguous
//   at u16 offset (rt*8 + kstep)*8192.
//   within tile: element (rl, kl) at  rl*64 + (((kl>>3) ^ (rl&7))<<3) + (kl&7)
// Staging is a LINEAR lane*16B gload_lds copy (linear LDS dest + pre-swizzled
// global source), so LDS gets the same XOR layout; fragment ds_read_b128 at
//   rl*128B + (((ks*4+quad) ^ (m16&7))*16B)
// spreads 64 lanes uniformly over all 32 banks.

// FUSED prep: blocks [0, NPAD/4) pack B (pad rows zero) + mm[j]=||m_j||^2;
// blocks [NPAD/4, NPAD/4+QN/4) pack A as bf16(-q) + theta + cnt=0.
// Fusing removes one serial launch and overlaps qprep with prep's tail.
__global__ __launch_bounds__(256) void k_prep(const float* __restrict__ B,
                                              u16* __restrict__ Bpack,
                                              float* __restrict__ mm,
                                              const float* __restrict__ A,
                                              u16* __restrict__ Apack,
                                              float* __restrict__ theta,
                                              u32* __restrict__ cnt) {
  const int blk = blockIdx.x;
  if (blk < NPAD / 4) {
    int g = blk * 256 + threadIdx.x;
    int row = g >> 6, lane = g & 63;
    const int rt = row >> 7, rl = row & 127;
    const int kstep = lane >> 3, chunk = lane & 7;
    u16* dst = Bpack + (size_t)(rt * 8 + kstep) * 8192
             + rl * 64 + ((chunk ^ (rl & 7)) << 3);
    if (row < NN) {
      const float* r = B + (size_t)row * DD + lane * 8;
      float4 a = *(const float4*)&r[0];
      float4 b = *(const float4*)&r[4];
      ushort4 h0, h1;
      h0.x = f2bf(a.x); h0.y = f2bf(a.y); h0.z = f2bf(a.z); h0.w = f2bf(a.w);
      h1.x = f2bf(b.x); h1.y = f2bf(b.y); h1.z = f2bf(b.z); h1.w = f2bf(b.w);
      *(ushort4*)&dst[0] = h0; *(ushort4*)&dst[4] = h1;
      float s = a.x*a.x + a.y*a.y + a.z*a.z + a.w*a.w
              + b.x*b.x + b.y*b.y + b.z*b.z + b.w*b.w;
      #pragma unroll
      for (int off = 32; off; off >>= 1) s += __shfl_xor(s, off);
      if (lane == 0) mm[row] = s;
    } else {
      ushort4 z; z.x = 0; z.y = 0; z.z = 0; z.w = 0;
      *(ushort4*)&dst[0] = z; *(ushort4*)&dst[4] = z;
      if (lane == 0) mm[row] = 1e30f;
    }
  } else {
    int g = (blk - NPAD / 4) * 256 + threadIdx.x;
    int row = g >> 6, lane = g & 63;
    const int qt = row >> 7, rl = row & 127;
    const int kstep = lane >> 3, chunk = lane & 7;
    u16* dst = Apack + (size_t)(qt * 8 + kstep) * 8192
             + rl * 64 + ((chunk ^ (rl & 7)) << 3);
    const float* r = A + (size_t)row * DD + lane * 8;
    float4 a = *(const float4*)&r[0];
    float4 b = *(const float4*)&r[4];
    ushort4 h0, h1;
    h0.x = f2bf(-a.x); h0.y = f2bf(-a.y); h0.z = f2bf(-a.z); h0.w = f2bf(-a.w);
    h1.x = f2bf(-b.x); h1.y = f2bf(-b.y); h1.z = f2bf(-b.z); h1.w = f2bf(-b.w);
    *(ushort4*)&dst[0] = h0; *(ushort4*)&dst[4] = h1;
    float s = a.x*a.x + a.y*a.y + a.z*a.z + a.w*a.w
            + b.x*b.x + b.y*b.y + b.z*b.z + b.w*b.w;
    #pragma unroll
    for (int off = 32; off; off >>= 1) s += __shfl_xor(s, off);
    if (lane == 0) {
      theta[row] = 256.0f - 2.9f * sqrtf(256.0f + s);
      cnt[row] = 0u;
    }
  }
}

// Screening GEMM — ROUND-1 CHAMPION, verbatim (280 us, 752 TF, 0 conflicts):
// 128x128 tile, BK=64, 4 waves (2x2), single-buffer LDS staged via
// global_load_lds width-16, 2-barrier K-loop, ~2.8 blocks/CU mutual overlap.
// Seven structural variants (deep pipelines, bigger tiles, 32x32 MFMA,
// hybrid operand routing, packed u32 cands) all measured slower on this
// shape (K=512 -> 8 K-steps; grid = 12x CU count).
__global__ __launch_bounds__(256, 2) void k_gemm(const u16* __restrict__ Apack,
                                                 const u16* __restrict__ Bpack,
                                                 const float* __restrict__ mm,
                                                 const float* __restrict__ theta,
                                                 u32* __restrict__ cnt,
                                                 u64* __restrict__ cands) {
  __shared__ __align__(16) u16 Alds[8192];   // 128 rows x 64 k, XOR8-swizzled
  __shared__ __align__(16) u16 Blds[8192];
  const int tid  = threadIdx.x;
  const int lane = tid & 63;
  const int w    = tid >> 6;
  const int wq   = w >> 1, wn = w & 1;
  const int quad = lane >> 4, m16 = lane & 15;

  // XCD-band mapping: b%8 = XCD x, each XCD owns col-tiles [x*98, x*98+98);
  // 16 consecutive same-XCD blocks share one B-tile (L2-resident).
  const int b  = blockIdx.x;
  const int x  = b & 7, kk_ = b >> 3;
  const int ct = x * 98 + (kk_ >> 4);
  const int qt = kk_ & 15;
  const int q0   = qt * 128;
  const int col0 = ct * 128;

  f32x4_t acc[4][4];
  #pragma unroll
  for (int j = 0; j < 4; j++) {
    float mv = 0.5f * mm[col0 + wn * 64 + j * 16 + m16];
    #pragma unroll
    for (int i = 0; i < 4; i++) { acc[i][j][0] = mv; acc[i][j][1] = mv; acc[i][j][2] = mv; acc[i][j][3] = mv; }
  }

  const u16* gA = Apack + (size_t)qt * 65536;   // 8 ksteps x 8192 u16
  const u16* gB = Bpack + (size_t)ct * 65536;

  const int sa  = m16 & 7;
  const int ch0 = ((0 * 4 + quad) ^ sa) << 3;   // u16 offset of 16B chunk, ks=0
  const int ch1 = ((1 * 4 + quad) ^ sa) << 3;   // ks=1
  const int aBase = (wq * 64 + m16) * 64;
  const int bBase = (wn * 64 + m16) * 64;
  const int c0 = w * 4;                          // this wave's four 1KB chunks

  #pragma unroll 1
  for (int kstep = 0; kstep < 8; ++kstep) {
    if (kstep) __syncthreads();                  // LDS reuse guard
    const u16* sA = gA + kstep * 8192;
    const u16* sB = gB + kstep * 8192;
    #pragma unroll
    for (int l = 0; l < 4; ++l) {
      const int c = c0 + l;
      gload_lds16(sA + c * 512 + lane * 8, &Alds[c * 512]);
      gload_lds16(sB + c * 512 + lane * 8, &Blds[c * 512]);
    }
    __syncthreads();                             // vmcnt(0) drain + barrier

    bf16x8_t af[2][4], bff[2][4];
    #pragma unroll
    for (int i = 0; i < 4; ++i) {
      af[0][i] = *(const bf16x8_t*)&Alds[aBase + i * 1024 + ch0];
      af[1][i] = *(const bf16x8_t*)&Alds[aBase + i * 1024 + ch1];
    }
    #pragma unroll
    for (int j = 0; j < 4; ++j) {
      bff[0][j] = *(const bf16x8_t*)&Blds[bBase + j * 1024 + ch0];
      bff[1][j] = *(const bf16x8_t*)&Blds[bBase + j * 1024 + ch1];
    }
    #pragma unroll
    for (int ks = 0; ks < 2; ++ks)
      #pragma unroll
      for (int i = 0; i < 4; ++i)
        #pragma unroll
        for (int j = 0; j < 4; ++j)
          acc[i][j] = __builtin_amdgcn_mfma_f32_16x16x32_bf16(af[ks][i], bff[ks][j], acc[i][j], 0, 0, 0);
  }

  // epilogue: C/D layout col=lane&15, row=(lane>>4)*4+reg; rare-hit append.
  #pragma unroll
  for (int i = 0; i < 4; i++) {
    #pragma unroll
    for (int r = 0; r < 4; r++) {
      int qrow = q0 + wq * 64 + i * 16 + quad * 4 + r;
      float th = theta[qrow];
      #pragma unroll
      for (int j = 0; j < 4; j++) {
        float s = acc[i][j][r];
        if (s < th) {
          int col = col0 + wn * 64 + j * 16 + m16;
          u32 slot = atomicAdd(&cnt[qrow], 1u);
          if (slot < CAP)
            cands[(size_t)qrow * CAP + slot] = ((u64)qkey_of(s) << 32) | (u32)col;
        }
      }
    }
  }
}

// Per query: rank-select candidates -> top-64 by key, rescore exactly in
// fp64, bitonic-sort 64, mean of top-32 true_values.
__global__ __launch_bounds__(256) void k_merge(const u32* __restrict__ cnt,
                                               const u64* __restrict__ cands,
                                               const float* __restrict__ A,
                                               const float* __restrict__ B,
                                               const float* __restrict__ tv,
                                               float* __restrict__ out) {
  int tid = threadIdx.x, q = blockIdx.x;
  __shared__ u16 keys[CAP];
  __shared__ int idxs[CAP];
  __shared__ u32 hist[256], cum[256], scal[2];
  __shared__ int cand[64];
  __shared__ float qrow[512];
  __shared__ double dd[64];

  int c = (int)min(cnt[q], (u32)CAP);
  for (int i = tid; i < c; i += 256) {
    u64 e = cands[(size_t)q * CAP + i];
    keys[i] = (u16)(e >> 32);
    idxs[i] = (int)(u32)(e & 0xFFFFFFFFu);
  }
  __syncthreads();
  u32 kwant = (c < 64) ? (u32)c : 64u;
  if (c <= 64) {
    // fast path (block-uniform): all candidates survive; skip rank-select
    for (int i = tid; i < c; i += 256) cand[i] = idxs[i];
  } else {
    u32 kstar, need;
    rank_cutoff(keys, c, kwant, hist, cum, scal, tid, kstar, need);
    if (tid == 0) { scal[0] = 0; scal[1] = 0; }
    __syncthreads();
    for (int i = tid; i < c; i += 256) {
      u16 kk = keys[i];
      if (kk < (u16)kstar) { u32 p = atomicAdd(&scal[0], 1u); cand[p] = idxs[i]; }
      else if (kk == (u16)kstar) {
        u32 t = atomicAdd(&scal[1], 1u);
        if (t < need) { u32 p = atomicAdd(&scal[0], 1u); cand[p] = idxs[i]; }
      }
    }
  }
  for (int i = tid; i < 512; i += 256) qrow[i] = A[(size_t)q * DD + i];
  __syncthreads();
  const int NC = (int)kwant;

  int w = tid >> 6, lane = tid & 63;
  double qd[8];
  #pragma unroll
  for (int e = 0; e < 8; e++) qd[e] = (double)qrow[lane * 8 + e];
  #pragma unroll 2
  for (int cc = w; cc < 64; cc += 4) {
    if (cc < NC) {
      const float* mrow = B + (size_t)cand[cc] * DD;
      float4 m0 = *(const float4*)&mrow[lane * 8];
      float4 m1 = *(const float4*)&mrow[lane * 8 + 4];
      double a = 0.0, t;
      t = qd[0] - (double)m0.x; a = fma(t, t, a);
      t = qd[1] - (double)m0.y; a = fma(t, t, a);
      t = qd[2] - (double)m0.z; a = fma(t, t, a);
      t = qd[3] - (double)m0.w; a = fma(t, t, a);
      t = qd[4] - (double)m1.x; a = fma(t, t, a);
      t = qd[5] - (double)m1.y; a = fma(t, t, a);
      t = qd[6] - (double)m1.z; a = fma(t, t, a);
      t = qd[7] - (double)m1.w; a = fma(t, t, a);
      #pragma unroll
      for (int off = 32; off; off >>= 1) a += __shfl_xor(a, off);
      if (lane == 0) dd[cc] = a;
    } else {
      if (lane == 0) dd[cc] = 1e300;
    }
  }
  __syncthreads();
  if (w == 0) {
    double d = dd[lane];
    float v = (lane < NC) ? tv[cand[lane]] : 0.0f;
    #pragma unroll
    for (int k = 2; k <= 64; k <<= 1) {
      #pragma unroll
      for (int j = k >> 1; j > 0; j >>= 1) {
        int partner = lane ^ j;
        double od = __shfl_xor(d, j);
        float  ovv = __shfl_xor(v, j);
        bool up = ((lane & k) == 0);
        bool takeMin = (lane < partner) == up;
        bool sw = takeMin ? (od < d) : (od > d);
        if (sw) { d = od; v = ovv; }
      }
    }
    double s = (lane < 32) ? (double)v : 0.0;
    #pragma unroll
    for (int off = 32; off; off >>= 1) s += __shfl_xor(s, off);
    if (lane == 0) out[q] = (float)(s * (1.0 / 32.0));
  }
}

// ---- launcher ------------------------------------------------------------

extern "C" void kernel_launch(void* const* d_in, const int* in_sizes, int n_in,
                              void* d_out, int out_size, void* d_ws, size_t ws_size,
                              hipStream_t stream) {
  const float* A  = (const float*)d_in[0];   // h_query      [2048,512]
  const float* B  = (const float*)d_in[1];   // memory_embeds[100000,512]
  const float* tv = (const float*)d_in[2];   // true_values  [100000]
  float* out = (float*)d_out;                // [2048]
  char* ws = (char*)d_ws;
  // ws layout (~122 MB of ~800 MB)
  float* mm    = (float*)(ws);                  // 100352 f32
  u16*   Apack = (u16*)  (ws + 401408);         // 2048*512 bf16, tile-swizzled
  float* theta = (float*)(ws + 2498560);        // 2048 f32
  u32*   cnt   = (u32*)  (ws + 2506752);        // 2048 u32
  u16*   Bpack = (u16*)  (ws + 2514944);        // 100352*512 bf16, tile-swizzled
  u64*   cands = (u64*)  (ws + 105275392);      // 2048*1024 u64 (16.8 MB)

  k_prep <<<NPAD / 4 + QN / 4, 256, 0, stream>>>(B, Bpack, mm, A, Apack, theta, cnt);
  k_gemm <<<NCT * 16, 256, 0, stream>>>(Apack, Bpack, mm, theta, cnt, cands);
  k_merge<<<QN, 256, 0, stream>>>(cnt, cands, A, B, tv, out);
}